// Round 6
// baseline (13471.349 us; speedup 1.0000x reference)
//
#include <hip/hip_runtime.h>
#include <hip/hip_bf16.h>
#include <cstdint>

#define T_STEPS 100
#define BATCH 256
#define NIN 700
#define H1 2048
#define H2 2048
#define NOUT 20
#define KS 16           // K-split factor for l2 GEMM

typedef __attribute__((ext_vector_type(8))) short bf16x8;
typedef __attribute__((ext_vector_type(4))) float f32x4;
typedef unsigned long long ull;

__device__ __forceinline__ void async16(void* lds, const void* g) {
    __builtin_amdgcn_global_load_lds(
        (const __attribute__((address_space(1))) unsigned int*)g,
        (__attribute__((address_space(3))) unsigned int*)lds, 16, 0, 0);
}

__device__ __forceinline__ unsigned short f2bf(float x) {
    __hip_bfloat16 h = __float2bfloat16(x);
    return *(unsigned short*)&h;
}
__device__ __forceinline__ float bf2f(unsigned short u) {
    __hip_bfloat16 h = *(__hip_bfloat16*)&u;
    return __bfloat162float(h);
}

// ---------------- split W2|V into bf16 hi/mid/lo, layout [term][j][4096k] ----
__global__ __launch_bounds__(256) void split_kernel(
    const float* __restrict__ W2, const float* __restrict__ V,
    unsigned short* __restrict__ Bsplit)
{
    const size_t D = (size_t)2048 * 4096;
    size_t i = (size_t)blockIdx.x * 256 + threadIdx.x;
    int j = (int)(i >> 12), k = (int)(i & 4095);
    float w = (k < 2048) ? W2[(size_t)j * 2048 + k] : V[(size_t)j * 2048 + (k - 2048)];
    unsigned short h = f2bf(w);
    float r1 = w - bf2f(h);
    unsigned short m = f2bf(r1);
    float r2 = r1 - bf2f(m);
    unsigned short l = f2bf(r2);
    Bsplit[i] = h;
    Bsplit[D + i] = m;
    Bsplit[2 * D + i] = l;
}

// ---------------- split W1 into granule-major bf16 planes ------------------
__global__ __launch_bounds__(256) void w1split_kernel(
    const float* __restrict__ W1, unsigned short* __restrict__ W1f)
{
    const size_t P = (size_t)88 * 2048 * 8;   // elems per term
    int id = blockIdx.x * 256 + threadIdx.x;  // 0..180223
    int g = id >> 11, j = id & 2047;
    unsigned short h8[8], m8[8], l8[8];
    #pragma unroll
    for (int e = 0; e < 8; ++e) {
        int k = g * 8 + e;
        float v = (k < NIN) ? W1[(size_t)j * NIN + k] : 0.f;
        unsigned short h = f2bf(v); float r1 = v - bf2f(h);
        unsigned short m = f2bf(r1); float r2 = r1 - bf2f(m);
        h8[e] = h; m8[e] = m; l8[e] = f2bf(r2);
    }
    size_t base = (((size_t)g * 2048) + j) * 8;
    *(uint4*)(W1f + base)         = *(uint4*)h8;
    *(uint4*)(W1f + P + base)     = *(uint4*)m8;
    *(uint4*)(W1f + 2 * P + base) = *(uint4*)l8;
}

// ---------------- layer 1 via MFMA: x@W1.T (6-term bf16) + scan + bitpack ----
__global__ __launch_bounds__(256) void l1m_kernel(
    const float* __restrict__ data, const unsigned short* __restrict__ W1f,
    const float* __restrict__ b1,
    const float* __restrict__ p_beta1, const float* __restrict__ p_thr1,
    ull* __restrict__ s1bits)
{
    __shared__ __align__(16) char smem[33280];  // union: Af 21.5KB | Cw 4x8.3KB
    unsigned short* Af = (unsigned short*)smem; // [3 term][4 g][112 t][8]
    const int tid = threadIdx.x, lane = tid & 63, w = tid >> 6;
    const int n16 = lane & 15, q = lane >> 4;
    const int jt = blockIdx.x & 7, b = blockIdx.x >> 3;
    const int j0w = jt * 256 + w * 64;
    const float* xb = data + (size_t)b * (NIN * T_STEPS);
    const size_t P = (size_t)88 * 2048 * 8;

    f32x4 acc[7][4] = {};
    for (int c = 0; c < 22; ++c) {
        const int kbase = c * 32;
        for (int it = tid; it < 448; it += 256) {
            int g = it / 112, t = it - g * 112;
            unsigned short h8[8], m8[8], l8[8];
            #pragma unroll
            for (int e = 0; e < 8; ++e) {
                int k = kbase + g * 8 + e;
                float v = (t < T_STEPS && k < NIN) ? xb[(size_t)k * T_STEPS + t] : 0.f;
                unsigned short h = f2bf(v); float r1 = v - bf2f(h);
                unsigned short m = f2bf(r1); float r2 = r1 - bf2f(m);
                h8[e] = h; m8[e] = m; l8[e] = f2bf(r2);
            }
            unsigned short* dst = Af + g * 896 + t * 8;
            *(uint4*)(dst)        = *(uint4*)h8;
            *(uint4*)(dst + 3584) = *(uint4*)m8;
            *(uint4*)(dst + 7168) = *(uint4*)l8;
        }
        __syncthreads();
        bf16x8 bh[4], bm[4], bl[4];
        const size_t gq = (size_t)(c * 4 + q);
        #pragma unroll
        for (int n = 0; n < 4; ++n) {
            size_t off = (gq * 2048 + (size_t)(j0w + n * 16 + n16)) * 8;
            bh[n] = *(const bf16x8*)(W1f + off);
            bm[n] = *(const bf16x8*)(W1f + P + off);
            bl[n] = *(const bf16x8*)(W1f + 2 * P + off);
        }
        #pragma unroll
        for (int m = 0; m < 7; ++m) {
            const unsigned short* ap = Af + q * 896 + (m * 16 + n16) * 8;
            bf16x8 ah = *(const bf16x8*)(ap);
            bf16x8 am = *(const bf16x8*)(ap + 3584);
            bf16x8 al = *(const bf16x8*)(ap + 7168);
            #pragma unroll
            for (int n = 0; n < 4; ++n) {
                acc[m][n] = __builtin_amdgcn_mfma_f32_16x16x32_bf16(ah, bh[n], acc[m][n], 0, 0, 0);
                acc[m][n] = __builtin_amdgcn_mfma_f32_16x16x32_bf16(ah, bm[n], acc[m][n], 0, 0, 0);
                acc[m][n] = __builtin_amdgcn_mfma_f32_16x16x32_bf16(am, bh[n], acc[m][n], 0, 0, 0);
                acc[m][n] = __builtin_amdgcn_mfma_f32_16x16x32_bf16(ah, bl[n], acc[m][n], 0, 0, 0);
                acc[m][n] = __builtin_amdgcn_mfma_f32_16x16x32_bf16(al, bh[n], acc[m][n], 0, 0, 0);
                acc[m][n] = __builtin_amdgcn_mfma_f32_16x16x32_bf16(am, bm[n], acc[m][n], 0, 0, 0);
            }
        }
        __syncthreads();
    }
    float* Cw = (float*)smem + w * (32 * 65);
    const float beta1 = *p_beta1, thr1 = *p_thr1;
    const float b1j = b1[j0w + lane];
    float mem = 0.f;
    for (int s = 0; s < 4; ++s) {
        #pragma unroll
        for (int mm = 0; mm < 2; ++mm) {
            int m = s * 2 + mm;
            if (m < 7) {
                #pragma unroll
                for (int n = 0; n < 4; ++n)
                    #pragma unroll
                    for (int r = 0; r < 4; ++r)
                        Cw[(mm * 16 + q * 4 + r) * 65 + n * 16 + n16] = acc[m][n][r];
            }
        }
        int tcnt = (s < 3) ? 32 : 4;
        for (int tt = 0; tt < tcnt; ++tt) {
            float v = Cw[tt * 65 + lane];
            mem = fmaf(beta1, mem, v) + b1j;
            bool pred = (mem - thr1) > 0.f;
            ull mask = __ballot(pred);
            if (pred) mem -= thr1;
            if (lane == 0) {
                int tg = s * 32 + tt;
                s1bits[((size_t)tg * BATCH + b) * 32 + jt * 4 + w] = mask;
            }
        }
    }
}

// ---------------- fused step: l3(t-1) + GEMM partial + spin + fin ------------
// grid 512 = 32 nt x 16 ks, block 256/4 waves; launch_bounds(256,2) => all 512
// blocks co-resident (256 CU x 2) so the spin-barrier cannot deadlock.
__global__ __launch_bounds__(256, 2) void step_kernel(
    const ull* __restrict__ s1bits_t,
    const ull* __restrict__ srb_in,
    ull* __restrict__ srb_out,
    const unsigned short* __restrict__ Bsplit,
    float* __restrict__ Cpart,
    unsigned int* __restrict__ ctr,
    const float* __restrict__ b2,
    float* __restrict__ mem_r, float* __restrict__ ahp,
    const float* __restrict__ W3, const float* __restrict__ b3,
    float* __restrict__ mem2, float* __restrict__ out_prev,
    int do_l3,
    const float* p_beta_r, const float* p_thr_r,
    const float* p_back_beta, const float* p_alpha,
    const float* p_beta2, const float* p_thr2)
{
    __shared__ __align__(16) unsigned short Blds[64 * 64];   // 8 KB
    __shared__ float red[4][NOUT];
    const int bid = blockIdx.x;
    const int nt = bid & 31, ks = bid >> 5;
    const int n0 = nt << 6;
    const int tid = threadIdx.x;
    const int lane = tid & 63, w = tid >> 6;
    const int q = lane >> 4, n16 = lane & 15;

    // ---- layer 3 for previous step (block bid == batch b) ----
    if (do_l3 && bid < 256) {
        const int b = bid;
        ull wd = srb_in[(size_t)b * 32 + (tid >> 3)];
        unsigned int byv = (unsigned int)(wd >> ((tid & 7) << 3)) & 0xFFu;
        float s8[8];
        #pragma unroll
        for (int e = 0; e < 8; ++e) s8[e] = (float)((byv >> e) & 1u);
        #pragma unroll
        for (int o = 0; o < NOUT; ++o) {
            const float4* wp = (const float4*)(W3 + (size_t)o * 2048 + tid * 8);
            float4 wa = wp[0], wb = wp[1];
            float v = s8[0]*wa.x + s8[1]*wa.y + s8[2]*wa.z + s8[3]*wa.w
                    + s8[4]*wb.x + s8[5]*wb.y + s8[6]*wb.z + s8[7]*wb.w;
            #pragma unroll
            for (int msk = 32; msk > 0; msk >>= 1) v += __shfl_xor(v, msk, 64);
            if (lane == 0) red[w][o] = v;
        }
        __syncthreads();
        if (tid < NOUT) {
            const float beta2 = *p_beta2, thr2 = *p_thr2;
            float cur = red[0][tid] + red[1][tid] + red[2][tid] + red[3][tid] + b3[tid];
            float m = fmaf(beta2, mem2[b * NOUT + tid], cur);
            bool pred = (m - thr2) > 0.f;
            if (pred) m -= thr2;
            mem2[b * NOUT + tid] = m;
            out_prev[b * NOUT + tid] = pred ? 1.f : 0.f;
        }
        __syncthreads();
    }

    // ---- GEMM partial: C[256b x 64j], K-range [ks*768, ks*768+768) ----
    f32x4 acc[4][4] = {};
    const int fbase = ks * 768;
    for (int c = 0; c < 12; ++c) {
        const int f = fbase + (c << 6);
        const int term = f >> 12;
        const int kin = f & 4095;
        const int w64g = kin >> 6;
        const unsigned short* Bg = Bsplit + ((size_t)term << 23);
        #pragma unroll
        for (int i = 0; i < 2; ++i) {
            int d = (w << 7) + (i << 6) + lane;
            int row = d >> 3, g8 = d & 7;
            int k16s = g8 ^ (row & 7);
            const unsigned short* g = Bg + (size_t)(n0 + row) * 4096 + kin + (k16s << 3);
            async16(Blds + (((w << 7) + (i << 6)) << 3), (const void*)g);
        }
        ull wrd[4];
        #pragma unroll
        for (int i = 0; i < 4; ++i) {
            int row = (w << 6) + (i << 4) + n16;
            wrd[i] = (w64g < 32) ? s1bits_t[(size_t)row * 32 + w64g]
                                 : srb_in[(size_t)row * 32 + (w64g - 32)];
        }
        __syncthreads();
        #pragma unroll
        for (int kk = 0; kk < 2; ++kk) {
            const int bsel = (kk << 2) + q;
            bf16x8 af[4], bfr[4];
            #pragma unroll
            for (int i = 0; i < 4; ++i) {
                unsigned int byv = (unsigned int)(wrd[i] >> (bsel << 3)) & 0xFFu;
                union { unsigned int u[4]; bf16x8 v; } U;
                #pragma unroll
                for (int p2 = 0; p2 < 4; ++p2)
                    U.u[p2] = (((byv >> (2*p2)) & 1u) ? 0x3F80u : 0u)
                            | (((byv >> (2*p2+1)) & 1u) ? 0x3F800000u : 0u);
                af[i] = U.v;
            }
            const int k16 = (kk << 2) + q;
            #pragma unroll
            for (int j = 0; j < 4; ++j) {
                int rb = (j << 4) + n16;
                bfr[j] = *(const bf16x8*)(Blds + (((rb << 3) + (k16 ^ (rb & 7))) << 3));
            }
            #pragma unroll
            for (int i = 0; i < 4; ++i)
                #pragma unroll
                for (int j = 0; j < 4; ++j)
                    acc[i][j] = __builtin_amdgcn_mfma_f32_16x16x32_bf16(af[i], bfr[j], acc[i][j], 0, 0, 0);
        }
        __syncthreads();
    }
    float* Cp = Cpart + ((size_t)ks << 19);
    #pragma unroll
    for (int i = 0; i < 4; ++i) {
        int rg = (w << 6) + (i << 4) + (q << 2);
        #pragma unroll
        for (int j = 0; j < 4; ++j) {
            int cg = n0 + (j << 4) + n16;
            #pragma unroll
            for (int r = 0; r < 4; ++r)
                Cp[(size_t)(rg + r) * 2048 + cg] = acc[i][j][r];
        }
    }

    // ---- publish partial, spin until all 512 done ----
    __syncthreads();
    if (tid == 0) {
        __threadfence();
        __hip_atomic_fetch_add(ctr, 1u, __ATOMIC_ACQ_REL, __HIP_MEMORY_SCOPE_AGENT);
        while (__hip_atomic_load(ctr, __ATOMIC_ACQUIRE, __HIP_MEMORY_SCOPE_AGENT) < 512u)
            __builtin_amdgcn_s_sleep(2);
    }
    __syncthreads();

    // ---- fin: 16 (b, j-word) units per block, fixed-order partial sum ----
    const float beta_r = *p_beta_r, thr_r = *p_thr_r;
    const float bb = *p_back_beta, al = *p_alpha;
    #pragma unroll
    for (int it = 0; it < 4; ++it) {
        int u = bid * 16 + w * 4 + it;
        int b = u >> 5, word = u & 31;
        size_t cidx = (size_t)b * 2048 + (word << 6) + lane;
        float x = 0.f;
        #pragma unroll
        for (int p2 = 0; p2 < KS; ++p2) x += Cpart[((size_t)p2 << 19) + cidx];
        float cur = x + b2[(word << 6) + lane];
        float a = ahp[cidx];
        float m = fmaf(beta_r, mem_r[cidx], cur) - a;
        bool pred = (m - thr_r) > 0.f;
        ull mask = __ballot(pred);
        float s = pred ? 1.f : 0.f;
        if (pred) m -= thr_r;
        mem_r[cidx] = m;
        ahp[cidx] = fmaf(bb, a, al * s);
        if (lane == 0) srb_out[(size_t)b * 32 + word] = mask;
    }
}

// ---------------- tail layer 3 for t = T-1 ----
__global__ __launch_bounds__(256) void l3tail_kernel(
    const ull* __restrict__ srb_in,
    const float* __restrict__ W3, const float* __restrict__ b3,
    float* __restrict__ mem2, float* __restrict__ out_t,
    const float* __restrict__ p_beta2, const float* __restrict__ p_thr2)
{
    __shared__ float red[4][NOUT];
    const int b = blockIdx.x, tid = threadIdx.x;
    const int lane = tid & 63, w = tid >> 6;
    ull wd = srb_in[(size_t)b * 32 + (tid >> 3)];
    unsigned int byv = (unsigned int)(wd >> ((tid & 7) << 3)) & 0xFFu;
    float s8[8];
    #pragma unroll
    for (int e = 0; e < 8; ++e) s8[e] = (float)((byv >> e) & 1u);
    #pragma unroll
    for (int o = 0; o < NOUT; ++o) {
        const float4* wp = (const float4*)(W3 + (size_t)o * 2048 + tid * 8);
        float4 wa = wp[0], wb = wp[1];
        float v = s8[0]*wa.x + s8[1]*wa.y + s8[2]*wa.z + s8[3]*wa.w
                + s8[4]*wb.x + s8[5]*wb.y + s8[6]*wb.z + s8[7]*wb.w;
        #pragma unroll
        for (int msk = 32; msk > 0; msk >>= 1) v += __shfl_xor(v, msk, 64);
        if (lane == 0) red[w][o] = v;
    }
    __syncthreads();
    if (tid < NOUT) {
        const float beta2 = *p_beta2, thr2 = *p_thr2;
        float cur = red[0][tid] + red[1][tid] + red[2][tid] + red[3][tid] + b3[tid];
        float m = fmaf(beta2, mem2[b * NOUT + tid], cur);
        bool pred = (m - thr2) > 0.f;
        if (pred) m -= thr2;
        mem2[b * NOUT + tid] = m;
        out_t[b * NOUT + tid] = pred ? 1.f : 0.f;
    }
}

extern "C" void kernel_launch(void* const* d_in, const int* in_sizes, int n_in,
                              void* d_out, int out_size, void* d_ws, size_t ws_size,
                              hipStream_t stream)
{
    const float* data   = (const float*)d_in[0];
    const float* W1     = (const float*)d_in[1];
    const float* b1     = (const float*)d_in[2];
    const float* W2     = (const float*)d_in[3];
    const float* b2     = (const float*)d_in[4];
    const float* V      = (const float*)d_in[5];
    const float* W3     = (const float*)d_in[6];
    const float* b3     = (const float*)d_in[7];
    const float* beta1  = (const float*)d_in[8];
    const float* thr1   = (const float*)d_in[9];
    const float* beta_r = (const float*)d_in[10];
    const float* thr_r  = (const float*)d_in[11];
    const float* back_beta = (const float*)d_in[12];
    const float* alpha  = (const float*)d_in[13];
    const float* beta2  = (const float*)d_in[14];
    const float* thr2   = (const float*)d_in[15];
    float* out = (float*)d_out;
    (void)in_sizes; (void)n_in; (void)out_size; (void)ws_size;

    char* p = (char*)d_ws;
    auto carve = [&](size_t bytes) {
        char* r = p; p += (bytes + 255) & ~(size_t)255; return r;
    };
    ull* s1bits = (ull*)carve((size_t)T_STEPS*BATCH*32*8);                   // 6.55 MB
    ull* srb0   = (ull*)carve((size_t)BATCH*32*8);
    ull* srb1   = (ull*)carve((size_t)BATCH*32*8);
    float* mem_r = (float*)carve((size_t)BATCH*H2*4);
    float* ahp   = (float*)carve((size_t)BATCH*H2*4);
    float* mem2  = (float*)carve((size_t)BATCH*NOUT*4);
    unsigned short* Bsplit = (unsigned short*)carve((size_t)3*2048*4096*2);  // 50.3 MB
    float* Cpart = (float*)carve((size_t)KS*BATCH*H2*4);                     // 33.6 MB
    unsigned short* W1f = (unsigned short*)carve((size_t)3*88*2048*8*2);     // 8.65 MB
    unsigned int* ctrs  = (unsigned int*)carve((size_t)T_STEPS*4);

    hipMemsetAsync(srb0, 0, (size_t)BATCH*32*8, stream);
    hipMemsetAsync(mem_r, 0, (size_t)BATCH*H2*4, stream);
    hipMemsetAsync(ahp,  0, (size_t)BATCH*H2*4, stream);
    hipMemsetAsync(mem2, 0, (size_t)BATCH*NOUT*4, stream);
    hipMemsetAsync(ctrs, 0, (size_t)T_STEPS*4, stream);

    split_kernel<<<(2048*4096)/256, 256, 0, stream>>>(W2, V, Bsplit);
    w1split_kernel<<<704, 256, 0, stream>>>(W1, W1f);
    l1m_kernel<<<2048, 256, 0, stream>>>(data, W1f, b1, beta1, thr1, s1bits);

    ull* srb[2] = {srb0, srb1};
    for (int t = 0; t < T_STEPS; ++t) {
        const ull* sin = srb[t & 1];
        ull* sout = srb[(t + 1) & 1];
        float* out_prev = out + (size_t)(t > 0 ? t - 1 : 0) * (BATCH * NOUT);
        step_kernel<<<512, 256, 0, stream>>>(
            s1bits + (size_t)t*BATCH*32, sin, sout, Bsplit, Cpart, ctrs + t,
            b2, mem_r, ahp, W3, b3, mem2, out_prev, (t > 0) ? 1 : 0,
            beta_r, thr_r, back_beta, alpha, beta2, thr2);
    }
    // t=99 wrote srb[0]
    l3tail_kernel<<<256, 256, 0, stream>>>(srb0, W3, b3, mem2,
                                           out + (size_t)(T_STEPS-1)*(BATCH*NOUT),
                                           beta2, thr2);
}